// Round 4
// baseline (3866.562 us; speedup 1.0000x reference)
//
#include <hip/hip_runtime.h>
#include <stdint.h>

#define T_TOK 32768
#define H_DIM 1024
#define NH    12
#define HK    64
#define HV    128
#define KD    768
#define VD    1536
#define NSEG  16
#define NCOL  2432   // GEMM logical N: 768 k + 1536 v + 24 ba + pad -> 19*128
#define FEAT  48
#define CHUNK_M 4096

typedef unsigned int uint;
typedef unsigned short ushort;

typedef short bf16x8_t __attribute__((ext_vector_type(8)));
typedef float f32x4_t  __attribute__((ext_vector_type(4)));

__device__ __forceinline__ ushort f2b(float f){
  uint u = __float_as_uint(f);
  u += 0x7fffu + ((u>>16)&1u);           // round-to-nearest-even
  return (ushort)(u>>16);
}
__device__ __forceinline__ float b2f(ushort u){ return __uint_as_float(((uint)u)<<16); }
__device__ __forceinline__ void unpack2(uint u, float&a, float&b){
  a = __uint_as_float(u<<16); b = __uint_as_float(u & 0xffff0000u);
}
__device__ __forceinline__ float sigm(float x){ return 1.f/(1.f + __expf(-x)); }
__device__ __forceinline__ float silu(float x){ return x * sigm(x); }

// ---------------- seg_id ----------------
__global__ void segk(const int* __restrict__ cu, int* __restrict__ seg){
  int t = blockIdx.x*256 + threadIdx.x;
  if (t >= T_TOK) return;
  int s = 0;
  #pragma unroll
  for (int i=1;i<=NSEG;i++) s += (cu[i] <= t) ? 1 : 0;
  seg[t] = s;
}

// ---------------- stage A (chunked, f32 in): h = feat@W_in + b_in ; hn = zc_rmsnorm(h)
// hn chunk written bf16; residual h (f32) at seg-end rows; hn (f32) at rows te-3..te
__global__ __launch_bounds__(256,1) void stage_a(const float* __restrict__ x,
   const int* __restrict__ atype, const float* __restrict__ ac_table,
   const float* __restrict__ W_in, const float* __restrict__ b_in,
   const float* __restrict__ norm_w, const int* __restrict__ seg, int row_base,
   ushort* __restrict__ hn, float* __restrict__ h_end, float* __restrict__ hn_ends)
{
  __shared__ float feat[8][FEAT];
  __shared__ float hbuf[8][H_DIM];
  __shared__ float red[8];
  int tid = threadIdx.x;
  int base = row_base + blockIdx.x*8;      // global row of slot 0
  int lbase = blockIdx.x*8;                // local row in hn chunk
  if (tid < 8) red[tid] = 0.f;
  for (int idx=tid; idx<8*FEAT; idx+=256){
    int rr = idx / FEAT, i = idx % FEAT;
    int t = base + rr;
    float v;
    if (i < 16) v = x[t*16 + i];
    else { int s = seg[t]; int a = atype[s]; v = ac_table[a*32 + (i-16)]; }
    feat[rr][i] = v;
  }
  __syncthreads();
  int c0 = tid*4;
  int lane = tid & 63;
  float4 bi = *(const float4*)&b_in[c0];
  for (int rc=0; rc<2; rc++){
    float acc[4][4];
    #pragma unroll
    for (int r4=0;r4<4;r4++){ acc[r4][0]=bi.x; acc[r4][1]=bi.y; acc[r4][2]=bi.z; acc[r4][3]=bi.w; }
    for (int i=0;i<FEAT;i++){
      float4 wu = *(const float4*)&W_in[i*H_DIM + c0];
      #pragma unroll
      for (int r4=0;r4<4;r4++){
        float f = feat[rc*4+r4][i];
        acc[r4][0] = fmaf(f,wu.x,acc[r4][0]);
        acc[r4][1] = fmaf(f,wu.y,acc[r4][1]);
        acc[r4][2] = fmaf(f,wu.z,acc[r4][2]);
        acc[r4][3] = fmaf(f,wu.w,acc[r4][3]);
      }
    }
    #pragma unroll
    for (int r4=0;r4<4;r4++){
      int rr = rc*4+r4;
      float sq = acc[r4][0]*acc[r4][0] + acc[r4][1]*acc[r4][1]
               + acc[r4][2]*acc[r4][2] + acc[r4][3]*acc[r4][3];
      #pragma unroll
      for (int off=1; off<64; off<<=1) sq += __shfl_xor(sq, off);
      if (lane==0) atomicAdd(&red[rr], sq);
      hbuf[rr][c0]=acc[r4][0]; hbuf[rr][c0+1]=acc[r4][1];
      hbuf[rr][c0+2]=acc[r4][2]; hbuf[rr][c0+3]=acc[r4][3];
    }
  }
  __syncthreads();
  float4 nw = *(const float4*)&norm_w[c0];
  for (int rr=0; rr<8; rr++){
    int t = base + rr;
    float sc = rsqrtf(red[rr]*(1.f/1024.f) + 1e-6f);
    float h0=hbuf[rr][c0], h1=hbuf[rr][c0+1], h2=hbuf[rr][c0+2], h3=hbuf[rr][c0+3];
    float n0=h0*sc*(1.f+nw.x), n1=h1*sc*(1.f+nw.y);
    float n2=h2*sc*(1.f+nw.z), n3=h3*sc*(1.f+nw.w);
    uint2 ov; ov.x = (uint)f2b(n0) | ((uint)f2b(n1)<<16);
    ov.y = (uint)f2b(n2) | ((uint)f2b(n3)<<16);
    *(uint2*)&hn[(size_t)(lbase+rr)*H_DIM + c0] = ov;
    int sgt = seg[t];
    bool isend = (t == T_TOK-1) || (seg[t+1] != sgt);
    if (isend){
      float* he = h_end + (size_t)sgt*H_DIM + c0;
      he[0]=h0; he[1]=h1; he[2]=h2; he[3]=h3;
    }
    // save f32 hn rows te-3..te per segment (slot 3-d where t = te-d)
    #pragma unroll
    for (int d=0; d<4; d++){
      int td = t + d;
      if (td < T_TOK && seg[td] == sgt){
        bool end2 = (td == T_TOK-1) || (seg[td+1] != sgt);
        if (end2){
          float* hd = hn_ends + ((size_t)sgt*4 + (3-d))*H_DIM + c0;
          hd[0]=n0; hd[1]=n1; hd[2]=n2; hd[3]=n3;
        }
      }
    }
  }
}

// ---------------- build fused transposed weight wt[n][k] (f32 -> bf16) ----------------
__global__ void build_wt(const float* __restrict__ Wk, const float* __restrict__ Wv,
                         const float* __restrict__ Wb, const float* __restrict__ Wa,
                         ushort* __restrict__ wt)
{
  int idx = blockIdx.x*256 + threadIdx.x;      // idx = n*1024 + k
  int n = idx >> 10, k = idx & 1023;
  float v;
  if      (n < 768)  v = Wk[k*768 + n];
  else if (n < 2304) v = Wv[k*1536 + (n-768)];
  else if (n < 2316) v = Wb[k*12 + (n-2304)];
  else if (n < 2328) v = Wa[k*12 + (n-2316)];
  else               v = 0.f;
  wt[idx] = f2b(v);
}

// ---------------- chunked MFMA GEMM over hn_chunk, outputs kpre/vpre (bf16), ba (f32) --
__global__ __launch_bounds__(256,1) void gemm_bf16(const ushort* __restrict__ A,
    const ushort* __restrict__ Bt, int row_base,
    ushort* __restrict__ kpre, ushort* __restrict__ vpre, float* __restrict__ ba)
{
  const int K = H_DIM;
  __shared__ ushort As[128*40];
  __shared__ ushort Bs[128*40];
  int tid = threadIdx.x;
  const int ntile = NCOL >> 7;   // 19
  int mt = blockIdx.x / ntile, nt = blockIdx.x % ntile;
  int m0 = mt<<7, n0 = nt<<7;    // m0 is LOCAL to chunk
  int r = tid>>2, c8 = (tid&3)<<3;
  const ushort* pa0 = A  + (size_t)(m0 + r)*K + c8;
  const ushort* pa1 = A  + (size_t)(m0 + r + 64)*K + c8;
  const ushort* pb0 = Bt + (size_t)(n0 + r)*K + c8;
  const ushort* pb1 = Bt + (size_t)(n0 + r + 64)*K + c8;
  int lane = tid & 63;
  int wv = tid >> 6; int wm = (wv>>1)<<6, wn = (wv&1)<<6;
  int mloc = lane & 15, q8 = (lane>>4)<<3;
  f32x4_t acc[4][4];
  f32x4_t zero = {0.f,0.f,0.f,0.f};
  #pragma unroll
  for (int i=0;i<4;i++)
    #pragma unroll
    for (int j=0;j<4;j++) acc[i][j] = zero;
  for (int kk=0; kk<K; kk+=32){
    uint4 a0 = *(const uint4*)(pa0 + kk);
    uint4 a1 = *(const uint4*)(pa1 + kk);
    uint4 b0 = *(const uint4*)(pb0 + kk);
    uint4 b1 = *(const uint4*)(pb1 + kk);
    __syncthreads();
    *(uint4*)&As[r*40 + c8] = a0;
    *(uint4*)&As[(r+64)*40 + c8] = a1;
    *(uint4*)&Bs[r*40 + c8] = b0;
    *(uint4*)&Bs[(r+64)*40 + c8] = b1;
    __syncthreads();
    bf16x8_t af[4], bfr[4];
    #pragma unroll
    for (int i=0;i<4;i++){
      af[i]  = *(const bf16x8_t*)&As[(wm + i*16 + mloc)*40 + q8];
      bfr[i] = *(const bf16x8_t*)&Bs[(wn + i*16 + mloc)*40 + q8];
    }
    #pragma unroll
    for (int i=0;i<4;i++)
      #pragma unroll
      for (int j=0;j<4;j++)
        acc[i][j] = __builtin_amdgcn_mfma_f32_16x16x32_bf16(af[i], bfr[j], acc[i][j], 0,0,0);
  }
  int rq = (lane>>4)<<2;
  if (nt < 18){
    ushort* dst; int nstr, cbase;
    if (nt < 6) { dst = kpre; nstr = KD; cbase = n0; }
    else        { dst = vpre; nstr = VD; cbase = n0 - KD; }
    #pragma unroll
    for (int i=0;i<4;i++){
      #pragma unroll
      for (int j=0;j<4;j++){
        int colg = cbase + wn + j*16 + mloc;
        #pragma unroll
        for (int rg=0; rg<4; rg++){
          int rowg = row_base + m0 + wm + i*16 + rq + rg;
          dst[(size_t)rowg*nstr + colg] = f2b(acc[i][j][rg]);
        }
      }
    }
  } else {
    #pragma unroll
    for (int i=0;i<4;i++){
      #pragma unroll
      for (int j=0;j<4;j++){
        int cl = wn + j*16 + mloc;        // 0..127 within tile
        if (cl >= 24) continue;
        #pragma unroll
        for (int rg=0; rg<4; rg++){
          int rowg = row_base + m0 + wm + i*16 + rq + rg;
          ba[(size_t)rowg*32 + cl] = acc[i][j][rg];
        }
      }
    }
  }
}

// ---------------- decay/beta from ba (f32) ----------------
__global__ void dbk(const float* __restrict__ ba, const float* __restrict__ A_log,
                    const float* __restrict__ dt_bias, float2* __restrict__ db)
{
  int idx = blockIdx.x*256 + threadIdx.x;
  if (idx >= T_TOK*NH) return;
  int t = idx / NH, hh = idx % NH;
  float bp = ba[(size_t)t*32 + hh];
  float ap = ba[(size_t)t*32 + 12 + hh] + dt_bias[hh];
  float beta = sigm(bp);
  float sp = (ap > 20.f) ? ap : log1pf(__expf(ap));
  float dec = __expf(-__expf(A_log[hh]) * sp);
  float2 o; o.x = dec; o.y = beta;
  db[idx] = o;
}

// ---------------- side: save 3 predecessor rows per 64-row conv block ----------------
__global__ void side_k(const ushort* __restrict__ kpre, const ushort* __restrict__ vpre,
                       ushort* __restrict__ side)
{
  int b = blockIdx.x;                 // T/64 blocks
  int base = b*64;
  for (int idx=threadIdx.x; idx<3*2304; idx+=256){
    int jrow = idx / 2304, c = idx % 2304;
    int t0 = base - 3 + jrow;
    ushort v = 0;
    if (t0 >= 0)
      v = (c < KD) ? kpre[(size_t)t0*KD + c] : vpre[(size_t)t0*VD + (c-KD)];
    side[(size_t)(b*3 + jrow)*2304 + c] = v;
  }
}

// ---------------- conv+silu (+l2norm for k) IN PLACE on kpre/vpre ----------------
__global__ __launch_bounds__(256,1) void conv_ip(ushort* __restrict__ kpre,
   ushort* __restrict__ vpre, const ushort* __restrict__ side,
   const int* __restrict__ seg, const float* __restrict__ ckw, const float* __restrict__ cvw)
{
  int tid = threadIdx.x;
  int b = blockIdx.x;
  int base = b * 64;
  float w[9][4];
  int cj[9];
  #pragma unroll
  for (int j=0;j<9;j++){
    int c = tid + 256*j;
    cj[j] = c;
    float4 wu = (c < KD) ? *(const float4*)&ckw[c*4] : *(const float4*)&cvw[(c-KD)*4];
    w[j][0]=wu.x; w[j][1]=wu.y; w[j][2]=wu.z; w[j][3]=wu.w;
  }
  float p[9][4];
  #pragma unroll
  for (int j=0;j<9;j++){
    p[j][1] = b2f(side[(size_t)(b*3+0)*2304 + cj[j]]);
    p[j][2] = b2f(side[(size_t)(b*3+1)*2304 + cj[j]]);
    p[j][3] = b2f(side[(size_t)(b*3+2)*2304 + cj[j]]);
  }
  int s1 = (base-3>=0) ? seg[base-3] : -1;
  int s2 = (base-2>=0) ? seg[base-2] : -1;
  int s3 = (base-1>=0) ? seg[base-1] : -1;
  int s0;
  for (int rr=0; rr<64; rr++){
    int t = base + rr;
    s0 = s1; s1 = s2; s2 = s3; s3 = seg[t];
    #pragma unroll
    for (int j=0;j<9;j++){
      p[j][0]=p[j][1]; p[j][1]=p[j][2]; p[j][2]=p[j][3];
      int c = cj[j];
      p[j][3] = (c < KD) ? b2f(kpre[(size_t)t*KD + c]) : b2f(vpre[(size_t)t*VD + (c-KD)]);
    }
    bool m0 = (s0==s3), m1 = (s1==s3), m2 = (s2==s3);
    #pragma unroll
    for (int j=0;j<9;j++){
      float val = p[j][3]*w[j][3];
      val += m2 ? p[j][2]*w[j][2] : 0.f;
      val += m1 ? p[j][1]*w[j][1] : 0.f;
      val += m0 ? p[j][0]*w[j][0] : 0.f;
      val = silu(val);
      int c = cj[j];
      if (j < 3){
        // l2norm per head: each (wave, j) covers exactly dims [head*64, head*64+64)
        float sq = val*val;
        #pragma unroll
        for (int off=1; off<64; off<<=1) sq += __shfl_xor(sq, off);
        float kn = val * rsqrtf(sq + 1e-6f);
        kpre[(size_t)t*KD + c] = f2b(kn);
      } else {
        vpre[(size_t)t*VD + (c-KD)] = f2b(val);
      }
    }
  }
}

// ---------------- q pre-GEMM at (up to) 64 saved rows (all f32) ----------------
__global__ __launch_bounds__(256,1) void qpre_k(const float* __restrict__ hn_ends,
   const float* __restrict__ Wq, const int* __restrict__ cu, float* __restrict__ qpre)
{
  __shared__ float hrow[H_DIM];
  int tid = threadIdx.x;
  int s = blockIdx.x >> 2, rr = blockIdx.x & 3;
  int t = cu[s+1] - 4 + rr;
  if (t >= 0)
    *(float4*)&hrow[tid*4] = *(const float4*)&hn_ends[(size_t)(s*4+rr)*H_DIM + tid*4];
  __syncthreads();
  for (int j=0;j<3;j++){
    int c = tid + 256*j;
    float acc = 0.f;
    if (t >= 0){
      for (int i0=0; i0<H_DIM; i0++)
        acc = fmaf(hrow[i0], Wq[(size_t)i0*KD + c], acc);
    }
    qpre[(size_t)(s*4+rr)*KD + c] = acc;
  }
}

// ---------------- q conv+silu+l2norm+scale at 16 end rows ----------------
__global__ __launch_bounds__(256,1) void qfin_k(const float* __restrict__ qpre,
   const float* __restrict__ cqw, const int* __restrict__ cu, const int* __restrict__ seg,
   float* __restrict__ qf)
{
  int tid = threadIdx.x;
  int s = blockIdx.x;
  int te = cu[s+1]-1;
  for (int j=0;j<3;j++){
    int c = tid + 256*j;
    float4 wu = *(const float4*)&cqw[c*4];
    float wv_[4] = {wu.x, wu.y, wu.z, wu.w};
    float val = 0.f;
    #pragma unroll
    for (int rr=0; rr<4; rr++){
      int t = te - 3 + rr;
      bool ok = (t >= 0) && (seg[t] == s);
      float pv = qpre[(size_t)(s*4+rr)*KD + c];
      val += ok ? pv * wv_[rr] : 0.f;
    }
    val = silu(val);
    float sq = val*val;
    #pragma unroll
    for (int off=1; off<64; off<<=1) sq += __shfl_xor(sq, off);
    qf[(size_t)s*KD + c] = val * rsqrtf(sq + 1e-6f) * 0.125f;   // HK^-0.5 folded
  }
}

// ---------------- gated delta-rule scan, one WG per (seg, head, v-block16) ------------
__global__ __launch_bounds__(128,1) void scan_k(const ushort* __restrict__ kpost,
   const ushort* __restrict__ vpost, const float2* __restrict__ db,
   const float* __restrict__ qf, const int* __restrict__ cu, float* __restrict__ obuf)
{
  int bid = blockIdx.x;            // s*96 + h*8 + vb
  int s = bid / 96; int rem = bid % 96; int h = rem >> 3; int vb = rem & 7;
  int tid = threadIdx.x;
  int vl = tid >> 3, kq = tid & 7;
  int start = cu[s], end = cu[s+1];
  float S[8];
  #pragma unroll
  for (int i=0;i<8;i++) S[i] = 0.f;
  size_t koff = (size_t)start*KD + h*HK + kq*8;
  size_t voff = (size_t)start*VD + h*HV + vb*16 + vl;
  size_t doff = (size_t)start*NH + h;
  uint4  kraw = *(const uint4*)(kpost + koff);
  float  vcur = b2f(vpost[voff]);
  float2 dbc  = db[doff];
  for (int t=start; t<end; t++){
    size_t adv = (t+1 < end) ? 1 : 0;
    koff += adv*KD; voff += adv*VD; doff += adv*NH;
    uint4  kn  = *(const uint4*)(kpost + koff);
    ushort vn  = vpost[voff];
    float2 dbn = db[doff];
    float kk[8];
    unpack2(kraw.x, kk[0], kk[1]); unpack2(kraw.y, kk[2], kk[3]);
    unpack2(kraw.z, kk[4], kk[5]); unpack2(kraw.w, kk[6], kk[7]);
    float a0=0.f, a1=0.f;
    #pragma unroll
    for (int i=0;i<4;i++){ a0 = fmaf(kk[i], S[i], a0); a1 = fmaf(kk[i+4], S[i+4], a1); }
    float kv = a0 + a1;
    kv += __shfl_xor(kv, 1); kv += __shfl_xor(kv, 2); kv += __shfl_xor(kv, 4);
    float d = dbc.x, bb = dbc.y;
    float wu = bb * (vcur - d*kv);
    #pragma unroll
    for (int i=0;i<8;i++) S[i] = fmaf(S[i], d, kk[i]*wu);
    kraw = kn; vcur = b2f(vn); dbc = dbn;
  }
  float op = 0.f;
  const float* qp = qf + (size_t)s*KD + h*HK + kq*8;
  #pragma unroll
  for (int i=0;i<8;i++) op = fmaf(qp[i], S[i], op);
  op += __shfl_xor(op, 1); op += __shfl_xor(op, 2); op += __shfl_xor(op, 4);
  if (kq == 0) obuf[(size_t)s*VD + h*HV + vb*16 + vl] = op;
}

// ---------------- o-norm + gate (hn_end @ Wg) + silu gating (f32) ----------------
__global__ __launch_bounds__(256,1) void gate_k(const float* __restrict__ obuf,
   const float* __restrict__ hn_ends, const float* __restrict__ Wg,
   const float* __restrict__ onw, const int* __restrict__ cu, float* __restrict__ og)
{
  __shared__ float red[4];
  __shared__ float hrow[H_DIM];
  int tid = threadIdx.x;
  int s = blockIdx.x / 6, ch = blockIdx.x % 6;
  int cc = ch*256 + tid;
  *(float4*)&hrow[tid*4] = *(const float4*)&hn_ends[(size_t)(s*4+3)*H_DIM + tid*4];
  float o = obuf[(size_t)s*VD + cc];
  float sq = o*o;
  #pragma unroll
  for (int off=1; off<64; off<<=1) sq += __shfl_xor(sq, off);
  int wv = tid>>6, lane = tid&63;
  if (lane==0) red[wv] = sq;
  __syncthreads();
  float ssum = (tid<128) ? (red[0]+red[1]) : (red[2]+red[3]);
  float onr = o * rsqrtf(ssum*(1.f/128.f) + 1e-5f) * onw[cc & 127];
  float acc = 0.f;
  for (int i0=0;i0<H_DIM;i0++)
    acc = fmaf(hrow[i0], Wg[(size_t)i0*VD + cc], acc);
  og[(size_t)s*VD + cc] = onr * acc * sigm(acc);
}

// ---------------- final: h = og@Wo + residual ; out = h@W_head + b_head (f32) ---------
__global__ __launch_bounds__(256,1) void final_k(const float* __restrict__ og,
   const float* __restrict__ Wo, const float* __restrict__ h_end,
   const float* __restrict__ W_head, const float* __restrict__ b_head,
   float* __restrict__ out)
{
  __shared__ float ogs[VD];
  __shared__ float redp[4];
  int tid = threadIdx.x;
  int s = blockIdx.x;
  for (int j=tid; j<VD; j+=256) ogs[j] = og[(size_t)s*VD + j];
  __syncthreads();
  int c0 = tid*4;
  float4 hh4 = *(const float4*)&h_end[(size_t)s*H_DIM + c0];
  float acc0 = hh4.x, acc1 = hh4.y, acc2 = hh4.z, acc3 = hh4.w;
  for (int j=0;j<VD;j++){
    float ov = ogs[j];
    float4 wo = *(const float4*)&Wo[(size_t)j*H_DIM + c0];
    acc0 = fmaf(ov,wo.x,acc0); acc1 = fmaf(ov,wo.y,acc1);
    acc2 = fmaf(ov,wo.z,acc2); acc3 = fmaf(ov,wo.w,acc3);
  }
  float4 wh = *(const float4*)&W_head[c0];
  float p = acc0*wh.x + acc1*wh.y + acc2*wh.z + acc3*wh.w;
  #pragma unroll
  for (int off=1; off<64; off<<=1) p += __shfl_xor(p, off);
  int wv = tid>>6, lane = tid&63;
  if (lane==0) redp[wv] = p;
  __syncthreads();
  if (tid==0) out[s] = redp[0]+redp[1]+redp[2]+redp[3] + b_head[0];
}

extern "C" void kernel_launch(void* const* d_in, const int* in_sizes, int n_in,
                              void* d_out, int out_size, void* d_ws, size_t ws_size,
                              hipStream_t stream)
{
  const float* x      = (const float*)d_in[0];
  const int*   cu     = (const int*)  d_in[1];
  const int*   atype  = (const int*)  d_in[2];
  const float* ac_tab = (const float*)d_in[3];
  const float* W_in   = (const float*)d_in[4];
  const float* b_in   = (const float*)d_in[5];
  const float* norm_w = (const float*)d_in[6];
  const float* Wq     = (const float*)d_in[7];
  const float* Wk     = (const float*)d_in[8];
  const float* Wv     = (const float*)d_in[9];
  const float* cqw    = (const float*)d_in[10];
  const float* ckw    = (const float*)d_in[11];
  const float* cvw    = (const float*)d_in[12];
  const float* Wb     = (const float*)d_in[13];
  const float* Wa     = (const float*)d_in[14];
  const float* A_log  = (const float*)d_in[15];
  const float* dt_b   = (const float*)d_in[16];
  const float* Wg     = (const float*)d_in[17];
  const float* onw    = (const float*)d_in[18];
  const float* Wo     = (const float*)d_in[19];
  const float* W_head = (const float*)d_in[20];
  const float* b_head = (const float*)d_in[21];
  float* out = (float*)d_out;

  // ---- workspace plan (~180 MiB peak, small buffers first) ----
  char* w = (char*)d_ws;
  int*    seg     = (int*)w;     w += (size_t)T_TOK*4;                //  0.13 MB
  float*  h_end   = (float*)w;   w += (size_t)NSEG*H_DIM*4;           //  64 KB
  float*  hn_ends = (float*)w;   w += (size_t)NSEG*4*H_DIM*4;         // 256 KB
  float*  qpre    = (float*)w;   w += (size_t)NSEG*4*KD*4;            // 192 KB
  float*  qf      = (float*)w;   w += (size_t)NSEG*KD*4;              //  48 KB
  float*  obuf    = (float*)w;   w += (size_t)NSEG*VD*4;              //  96 KB
  float*  og      = (float*)w;   w += (size_t)NSEG*VD*4;              //  96 KB
  float2* db      = (float2*)w;  w += (size_t)T_TOK*NH*8;             //  3.1 MB
  float*  ba      = (float*)w;   w += (size_t)T_TOK*32*4;             //  4.2 MB
  ushort* wt      = (ushort*)w;  w += (size_t)NCOL*H_DIM*2;           //  5.0 MB
  ushort* side    = (ushort*)w;  w += (size_t)(T_TOK/64)*3*2304*2;    //  7.1 MB
  ushort* hn_c    = (ushort*)w;  w += (size_t)CHUNK_M*H_DIM*2;        //  8.4 MB
  ushort* kpre    = (ushort*)w;  w += (size_t)T_TOK*KD*2;             // 50.3 MB
  ushort* vpre    = (ushort*)w;  w += (size_t)T_TOK*VD*2;             // 100.7 MB

  hipLaunchKernelGGL(segk,     dim3(T_TOK/256),        dim3(256), 0, stream, cu, seg);
  hipLaunchKernelGGL(build_wt, dim3((NCOL*H_DIM)/256), dim3(256), 0, stream, Wk, Wv, Wb, Wa, wt);
  // chunked stage_a + gemm (hn chunk buffer reused; stream order serializes)
  for (int c = 0; c < T_TOK/CHUNK_M; c++){
    int row_base = c*CHUNK_M;
    hipLaunchKernelGGL(stage_a,  dim3(CHUNK_M/8), dim3(256), 0, stream,
                       x, atype, ac_tab, W_in, b_in, norm_w, seg, row_base, hn_c, h_end, hn_ends);
    hipLaunchKernelGGL(gemm_bf16, dim3((CHUNK_M/128)*(NCOL/128)), dim3(256), 0, stream,
                       hn_c, wt, row_base, kpre, vpre, ba);
  }
  hipLaunchKernelGGL(dbk,      dim3((T_TOK*NH)/256),   dim3(256), 0, stream, ba, A_log, dt_b, db);
  hipLaunchKernelGGL(side_k,   dim3(T_TOK/64),         dim3(256), 0, stream, kpre, vpre, side);
  hipLaunchKernelGGL(conv_ip,  dim3(T_TOK/64),         dim3(256), 0, stream, kpre, vpre, side, seg, ckw, cvw);
  hipLaunchKernelGGL(qpre_k,   dim3(NSEG*4),           dim3(256), 0, stream, hn_ends, Wq, cu, qpre);
  hipLaunchKernelGGL(qfin_k,   dim3(NSEG),             dim3(256), 0, stream, qpre, cqw, cu, seg, qf);
  hipLaunchKernelGGL(scan_k,   dim3(NSEG*NH*8),        dim3(128), 0, stream, kpre, vpre, db, qf, cu, obuf);
  hipLaunchKernelGGL(gate_k,   dim3(NSEG*6),           dim3(256), 0, stream, obuf, hn_ends, Wg, onw, cu, og);
  hipLaunchKernelGGL(final_k,  dim3(NSEG),             dim3(256), 0, stream, og, Wo, h_end, W_head, b_head, out);
}

// Round 5
// 3769.379 us; speedup vs baseline: 1.0258x; 1.0258x over previous
//
#include <hip/hip_runtime.h>
#include <stdint.h>

#define T_TOK 32768
#define H_DIM 1024
#define NH    12
#define HK    64
#define HV    128
#define KD    768
#define VD    1536
#define NSEG  16
#define NCOL  2432   // GEMM logical N: 768 k + 1536 v + 24 ba + pad -> 19*128
#define FEAT  48
#define CHUNK_M 4096
#define SCAN_D 8

typedef unsigned int uint;
typedef unsigned short ushort;

typedef short bf16x8_t __attribute__((ext_vector_type(8)));
typedef float f32x4_t  __attribute__((ext_vector_type(4)));

__device__ __forceinline__ ushort f2b(float f){
  uint u = __float_as_uint(f);
  u += 0x7fffu + ((u>>16)&1u);           // round-to-nearest-even
  return (ushort)(u>>16);
}
__device__ __forceinline__ float b2f(ushort u){ return __uint_as_float(((uint)u)<<16); }
__device__ __forceinline__ void unpack2(uint u, float&a, float&b){
  a = __uint_as_float(u<<16); b = __uint_as_float(u & 0xffff0000u);
}
__device__ __forceinline__ float sigm(float x){ return 1.f/(1.f + __expf(-x)); }
__device__ __forceinline__ float silu(float x){ return x * sigm(x); }

// ---------------- seg_id ----------------
__global__ void segk(const int* __restrict__ cu, int* __restrict__ seg){
  int t = blockIdx.x*256 + threadIdx.x;
  if (t >= T_TOK) return;
  int s = 0;
  #pragma unroll
  for (int i=1;i<=NSEG;i++) s += (cu[i] <= t) ? 1 : 0;
  seg[t] = s;
}

// ---------------- stage A (chunked, f32 in): h = feat@W_in + b_in ; hn = zc_rmsnorm(h)
__global__ __launch_bounds__(256,1) void stage_a(const float* __restrict__ x,
   const int* __restrict__ atype, const float* __restrict__ ac_table,
   const float* __restrict__ W_in, const float* __restrict__ b_in,
   const float* __restrict__ norm_w, const int* __restrict__ seg, int row_base,
   ushort* __restrict__ hn, float* __restrict__ h_end, float* __restrict__ hn_ends)
{
  __shared__ float feat[8][FEAT];
  __shared__ float hbuf[8][H_DIM];
  __shared__ float red[8];
  int tid = threadIdx.x;
  int base = row_base + blockIdx.x*8;      // global row of slot 0
  int lbase = blockIdx.x*8;                // local row in hn chunk
  if (tid < 8) red[tid] = 0.f;
  for (int idx=tid; idx<8*FEAT; idx+=256){
    int rr = idx / FEAT, i = idx % FEAT;
    int t = base + rr;
    float v;
    if (i < 16) v = x[t*16 + i];
    else { int s = seg[t]; int a = atype[s]; v = ac_table[a*32 + (i-16)]; }
    feat[rr][i] = v;
  }
  __syncthreads();
  int c0 = tid*4;
  int lane = tid & 63;
  float4 bi = *(const float4*)&b_in[c0];
  for (int rc=0; rc<2; rc++){
    float acc[4][4];
    #pragma unroll
    for (int r4=0;r4<4;r4++){ acc[r4][0]=bi.x; acc[r4][1]=bi.y; acc[r4][2]=bi.z; acc[r4][3]=bi.w; }
    for (int i=0;i<FEAT;i++){
      float4 wu = *(const float4*)&W_in[i*H_DIM + c0];
      #pragma unroll
      for (int r4=0;r4<4;r4++){
        float f = feat[rc*4+r4][i];
        acc[r4][0] = fmaf(f,wu.x,acc[r4][0]);
        acc[r4][1] = fmaf(f,wu.y,acc[r4][1]);
        acc[r4][2] = fmaf(f,wu.z,acc[r4][2]);
        acc[r4][3] = fmaf(f,wu.w,acc[r4][3]);
      }
    }
    #pragma unroll
    for (int r4=0;r4<4;r4++){
      int rr = rc*4+r4;
      float sq = acc[r4][0]*acc[r4][0] + acc[r4][1]*acc[r4][1]
               + acc[r4][2]*acc[r4][2] + acc[r4][3]*acc[r4][3];
      #pragma unroll
      for (int off=1; off<64; off<<=1) sq += __shfl_xor(sq, off);
      if (lane==0) atomicAdd(&red[rr], sq);
      hbuf[rr][c0]=acc[r4][0]; hbuf[rr][c0+1]=acc[r4][1];
      hbuf[rr][c0+2]=acc[r4][2]; hbuf[rr][c0+3]=acc[r4][3];
    }
  }
  __syncthreads();
  float4 nw = *(const float4*)&norm_w[c0];
  for (int rr=0; rr<8; rr++){
    int t = base + rr;
    float sc = rsqrtf(red[rr]*(1.f/1024.f) + 1e-6f);
    float h0=hbuf[rr][c0], h1=hbuf[rr][c0+1], h2=hbuf[rr][c0+2], h3=hbuf[rr][c0+3];
    float n0=h0*sc*(1.f+nw.x), n1=h1*sc*(1.f+nw.y);
    float n2=h2*sc*(1.f+nw.z), n3=h3*sc*(1.f+nw.w);
    uint2 ov; ov.x = (uint)f2b(n0) | ((uint)f2b(n1)<<16);
    ov.y = (uint)f2b(n2) | ((uint)f2b(n3)<<16);
    *(uint2*)&hn[(size_t)(lbase+rr)*H_DIM + c0] = ov;
    int sgt = seg[t];
    bool isend = (t == T_TOK-1) || (seg[t+1] != sgt);
    if (isend){
      float* he = h_end + (size_t)sgt*H_DIM + c0;
      he[0]=h0; he[1]=h1; he[2]=h2; he[3]=h3;
    }
    #pragma unroll
    for (int d=0; d<4; d++){
      int td = t + d;
      if (td < T_TOK && seg[td] == sgt){
        bool end2 = (td == T_TOK-1) || (seg[td+1] != sgt);
        if (end2){
          float* hd = hn_ends + ((size_t)sgt*4 + (3-d))*H_DIM + c0;
          hd[0]=n0; hd[1]=n1; hd[2]=n2; hd[3]=n3;
        }
      }
    }
  }
}

// ---------------- build fused transposed weight wt[n][k] (f32 -> bf16) ----------------
__global__ void build_wt(const float* __restrict__ Wk, const float* __restrict__ Wv,
                         const float* __restrict__ Wb, const float* __restrict__ Wa,
                         ushort* __restrict__ wt)
{
  int idx = blockIdx.x*256 + threadIdx.x;      // idx = n*1024 + k
  int n = idx >> 10, k = idx & 1023;
  float v;
  if      (n < 768)  v = Wk[k*768 + n];
  else if (n < 2304) v = Wv[k*1536 + (n-768)];
  else if (n < 2316) v = Wb[k*12 + (n-2304)];
  else if (n < 2328) v = Wa[k*12 + (n-2316)];
  else               v = 0.f;
  wt[idx] = f2b(v);
}

// ---------------- chunked MFMA GEMM over hn_chunk, outputs kpre/vpre (bf16), ba (f32) --
__global__ __launch_bounds__(256,1) void gemm_bf16(const ushort* __restrict__ A,
    const ushort* __restrict__ Bt, int row_base,
    ushort* __restrict__ kpre, ushort* __restrict__ vpre, float* __restrict__ ba)
{
  const int K = H_DIM;
  __shared__ ushort As[128*40];
  __shared__ ushort Bs[128*40];
  int tid = threadIdx.x;
  const int ntile = NCOL >> 7;   // 19
  int mt = blockIdx.x / ntile, nt = blockIdx.x % ntile;
  int m0 = mt<<7, n0 = nt<<7;    // m0 is LOCAL to chunk
  int r = tid>>2, c8 = (tid&3)<<3;
  const ushort* pa0 = A  + (size_t)(m0 + r)*K + c8;
  const ushort* pa1 = A  + (size_t)(m0 + r + 64)*K + c8;
  const ushort* pb0 = Bt + (size_t)(n0 + r)*K + c8;
  const ushort* pb1 = Bt + (size_t)(n0 + r + 64)*K + c8;
  int lane = tid & 63;
  int wv = tid >> 6; int wm = (wv>>1)<<6, wn = (wv&1)<<6;
  int mloc = lane & 15, q8 = (lane>>4)<<3;
  f32x4_t acc[4][4];
  f32x4_t zero = {0.f,0.f,0.f,0.f};
  #pragma unroll
  for (int i=0;i<4;i++)
    #pragma unroll
    for (int j=0;j<4;j++) acc[i][j] = zero;
  for (int kk=0; kk<K; kk+=32){
    uint4 a0 = *(const uint4*)(pa0 + kk);
    uint4 a1 = *(const uint4*)(pa1 + kk);
    uint4 b0 = *(const uint4*)(pb0 + kk);
    uint4 b1 = *(const uint4*)(pb1 + kk);
    __syncthreads();
    *(uint4*)&As[r*40 + c8] = a0;
    *(uint4*)&As[(r+64)*40 + c8] = a1;
    *(uint4*)&Bs[r*40 + c8] = b0;
    *(uint4*)&Bs[(r+64)*40 + c8] = b1;
    __syncthreads();
    bf16x8_t af[4], bfr[4];
    #pragma unroll
    for (int i=0;i<4;i++){
      af[i]  = *(const bf16x8_t*)&As[(wm + i*16 + mloc)*40 + q8];
      bfr[i] = *(const bf16x8_t*)&Bs[(wn + i*16 + mloc)*40 + q8];
    }
    #pragma unroll
    for (int i=0;i<4;i++)
      #pragma unroll
      for (int j=0;j<4;j++)
        acc[i][j] = __builtin_amdgcn_mfma_f32_16x16x32_bf16(af[i], bfr[j], acc[i][j], 0,0,0);
  }
  int rq = (lane>>4)<<2;
  if (nt < 18){
    ushort* dst; int nstr, cbase;
    if (nt < 6) { dst = kpre; nstr = KD; cbase = n0; }
    else        { dst = vpre; nstr = VD; cbase = n0 - KD; }
    #pragma unroll
    for (int i=0;i<4;i++){
      #pragma unroll
      for (int j=0;j<4;j++){
        int colg = cbase + wn + j*16 + mloc;
        #pragma unroll
        for (int rg=0; rg<4; rg++){
          int rowg = row_base + m0 + wm + i*16 + rq + rg;
          dst[(size_t)rowg*nstr + colg] = f2b(acc[i][j][rg]);
        }
      }
    }
  } else {
    #pragma unroll
    for (int i=0;i<4;i++){
      #pragma unroll
      for (int j=0;j<4;j++){
        int cl = wn + j*16 + mloc;        // 0..127 within tile
        if (cl >= 24) continue;
        #pragma unroll
        for (int rg=0; rg<4; rg++){
          int rowg = row_base + m0 + wm + i*16 + rq + rg;
          ba[(size_t)rowg*32 + cl] = acc[i][j][rg];
        }
      }
    }
  }
}

// ---------------- decay/beta from ba (f32) ----------------
__global__ void dbk(const float* __restrict__ ba, const float* __restrict__ A_log,
                    const float* __restrict__ dt_bias, float2* __restrict__ db)
{
  int idx = blockIdx.x*256 + threadIdx.x;
  if (idx >= T_TOK*NH) return;
  int t = idx / NH, hh = idx % NH;
  float bp = ba[(size_t)t*32 + hh];
  float ap = ba[(size_t)t*32 + 12 + hh] + dt_bias[hh];
  float beta = sigm(bp);
  float sp = (ap > 20.f) ? ap : log1pf(__expf(ap));
  float dec = __expf(-__expf(A_log[hh]) * sp);
  float2 o; o.x = dec; o.y = beta;
  db[idx] = o;
}

// ---------------- side: save 3 predecessor rows per 64-row conv block ----------------
__global__ void side_k(const ushort* __restrict__ kpre, const ushort* __restrict__ vpre,
                       ushort* __restrict__ side)
{
  int b = blockIdx.x;                 // T/64 blocks
  int base = b*64;
  for (int idx=threadIdx.x; idx<3*2304; idx+=256){
    int jrow = idx / 2304, c = idx % 2304;
    int t0 = base - 3 + jrow;
    ushort v = 0;
    if (t0 >= 0)
      v = (c < KD) ? kpre[(size_t)t0*KD + c] : vpre[(size_t)t0*VD + (c-KD)];
    side[(size_t)(b*3 + jrow)*2304 + c] = v;
  }
}

// ---------------- conv+silu (+l2norm for k) IN PLACE on kpre/vpre ----------------
__global__ __launch_bounds__(256,1) void conv_ip(ushort* __restrict__ kpre,
   ushort* __restrict__ vpre, const ushort* __restrict__ side,
   const int* __restrict__ seg, const float* __restrict__ ckw, const float* __restrict__ cvw)
{
  int tid = threadIdx.x;
  int b = blockIdx.x;
  int base = b * 64;
  float w[9][4];
  int cj[9];
  #pragma unroll
  for (int j=0;j<9;j++){
    int c = tid + 256*j;
    cj[j] = c;
    float4 wu = (c < KD) ? *(const float4*)&ckw[c*4] : *(const float4*)&cvw[(c-KD)*4];
    w[j][0]=wu.x; w[j][1]=wu.y; w[j][2]=wu.z; w[j][3]=wu.w;
  }
  float p[9][4];
  #pragma unroll
  for (int j=0;j<9;j++){
    p[j][1] = b2f(side[(size_t)(b*3+0)*2304 + cj[j]]);
    p[j][2] = b2f(side[(size_t)(b*3+1)*2304 + cj[j]]);
    p[j][3] = b2f(side[(size_t)(b*3+2)*2304 + cj[j]]);
  }
  int s1 = (base-3>=0) ? seg[base-3] : -1;
  int s2 = (base-2>=0) ? seg[base-2] : -1;
  int s3 = (base-1>=0) ? seg[base-1] : -1;
  int s0;
  for (int rr=0; rr<64; rr++){
    int t = base + rr;
    s0 = s1; s1 = s2; s2 = s3; s3 = seg[t];
    #pragma unroll
    for (int j=0;j<9;j++){
      p[j][0]=p[j][1]; p[j][1]=p[j][2]; p[j][2]=p[j][3];
      int c = cj[j];
      p[j][3] = (c < KD) ? b2f(kpre[(size_t)t*KD + c]) : b2f(vpre[(size_t)t*VD + (c-KD)]);
    }
    bool m0 = (s0==s3), m1 = (s1==s3), m2 = (s2==s3);
    #pragma unroll
    for (int j=0;j<9;j++){
      float val = p[j][3]*w[j][3];
      val += m2 ? p[j][2]*w[j][2] : 0.f;
      val += m1 ? p[j][1]*w[j][1] : 0.f;
      val += m0 ? p[j][0]*w[j][0] : 0.f;
      val = silu(val);
      int c = cj[j];
      if (j < 3){
        float sq = val*val;
        #pragma unroll
        for (int off=1; off<64; off<<=1) sq += __shfl_xor(sq, off);
        float kn = val * rsqrtf(sq + 1e-6f);
        kpre[(size_t)t*KD + c] = f2b(kn);
      } else {
        vpre[(size_t)t*VD + (c-KD)] = f2b(val);
      }
    }
  }
}

// ---------------- q pre-GEMM at (up to) 64 saved rows (all f32) ----------------
__global__ __launch_bounds__(256,1) void qpre_k(const float* __restrict__ hn_ends,
   const float* __restrict__ Wq, const int* __restrict__ cu, float* __restrict__ qpre)
{
  __shared__ float hrow[H_DIM];
  int tid = threadIdx.x;
  int s = blockIdx.x >> 2, rr = blockIdx.x & 3;
  int t = cu[s+1] - 4 + rr;
  if (t >= 0)
    *(float4*)&hrow[tid*4] = *(const float4*)&hn_ends[(size_t)(s*4+rr)*H_DIM + tid*4];
  __syncthreads();
  for (int j=0;j<3;j++){
    int c = tid + 256*j;
    float acc = 0.f;
    if (t >= 0){
      for (int i0=0; i0<H_DIM; i0++)
        acc = fmaf(hrow[i0], Wq[(size_t)i0*KD + c], acc);
    }
    qpre[(size_t)(s*4+rr)*KD + c] = acc;
  }
}

// ---------------- q conv+silu+l2norm+scale at 16 end rows ----------------
__global__ __launch_bounds__(256,1) void qfin_k(const float* __restrict__ qpre,
   const float* __restrict__ cqw, const int* __restrict__ cu, const int* __restrict__ seg,
   float* __restrict__ qf)
{
  int tid = threadIdx.x;
  int s = blockIdx.x;
  int te = cu[s+1]-1;
  for (int j=0;j<3;j++){
    int c = tid + 256*j;
    float4 wu = *(const float4*)&cqw[c*4];
    float wv_[4] = {wu.x, wu.y, wu.z, wu.w};
    float val = 0.f;
    #pragma unroll
    for (int rr=0; rr<4; rr++){
      int t = te - 3 + rr;
      bool ok = (t >= 0) && (seg[t] == s);
      float pv = qpre[(size_t)(s*4+rr)*KD + c];
      val += ok ? pv * wv_[rr] : 0.f;
    }
    val = silu(val);
    float sq = val*val;
    #pragma unroll
    for (int off=1; off<64; off<<=1) sq += __shfl_xor(sq, off);
    qf[(size_t)s*KD + c] = val * rsqrtf(sq + 1e-6f) * 0.125f;   // HK^-0.5 folded
  }
}

// ---------------- gated delta-rule scan, deep-pipelined (D=8) ------------
// grid mapping: (s,h) = bid % 192, vb = bid / 192  -> all 8 vb of an (s,h)
// are 192 apart (192 % 8 == 0 -> same XCD by round-robin heuristic), so the
// shared k-stream hits that XCD's L2.
__global__ __launch_bounds__(128,1) void scan_k(const ushort* __restrict__ kpost,
   const ushort* __restrict__ vpost, const float2* __restrict__ db,
   const float* __restrict__ qf, const int* __restrict__ cu, float* __restrict__ obuf)
{
  int bid = blockIdx.x;
  int sh = bid % (NSEG*NH); int vb = bid / (NSEG*NH);
  int s = sh / NH, h = sh % NH;
  int tid = threadIdx.x;
  int vl = tid >> 3, kq = tid & 7;
  int start = cu[s], end = cu[s+1];
  float S[8];
  #pragma unroll
  for (int i=0;i<8;i++) S[i] = 0.f;
  const ushort* kbase = kpost + h*HK + kq*8;
  const ushort* vbase = vpost + h*HV + vb*16 + vl;
  const float2* dbase = db + h;

  uint4  kb[SCAN_D];
  ushort vbuf[SCAN_D];
  float2 dbb[SCAN_D];
  #pragma unroll
  for (int d=0; d<SCAN_D; d++){
    int tt = start + d; if (tt > end-1) tt = end-1;
    kb[d]  = *(const uint4*)(kbase + (size_t)tt*KD);
    vbuf[d]= vbase[(size_t)tt*VD];
    dbb[d] = dbase[(size_t)tt*NH];
  }
  int t = start;
  while (t < end){
    #pragma unroll
    for (int d=0; d<SCAN_D; d++){
      if (t < end){
        uint4  kcur = kb[d];
        float  vcur = b2f(vbuf[d]);
        float2 dbc  = dbb[d];
        // issue refill for t+D immediately (stays in flight across compute)
        int tn = t + SCAN_D; if (tn > end-1) tn = end-1;
        kb[d]  = *(const uint4*)(kbase + (size_t)tn*KD);
        vbuf[d]= vbase[(size_t)tn*VD];
        dbb[d] = dbase[(size_t)tn*NH];
        // compute step t
        float kk[8];
        unpack2(kcur.x, kk[0], kk[1]); unpack2(kcur.y, kk[2], kk[3]);
        unpack2(kcur.z, kk[4], kk[5]); unpack2(kcur.w, kk[6], kk[7]);
        float a0=0.f, a1=0.f;
        #pragma unroll
        for (int i=0;i<4;i++){ a0 = fmaf(kk[i], S[i], a0); a1 = fmaf(kk[i+4], S[i+4], a1); }
        float kv = a0 + a1;
        kv += __shfl_xor(kv, 1); kv += __shfl_xor(kv, 2); kv += __shfl_xor(kv, 4);
        float dd = dbc.x, bb = dbc.y;
        float wu = bb * (vcur - dd*kv);
        #pragma unroll
        for (int i=0;i<8;i++) S[i] = fmaf(S[i], dd, kk[i]*wu);
        t++;
      }
    }
  }
  float op = 0.f;
  const float* qp = qf + (size_t)s*KD + h*HK + kq*8;
  #pragma unroll
  for (int i=0;i<8;i++) op = fmaf(qp[i], S[i], op);
  op += __shfl_xor(op, 1); op += __shfl_xor(op, 2); op += __shfl_xor(op, 4);
  if (kq == 0) obuf[(size_t)s*VD + h*HV + vb*16 + vl] = op;
}

// ---------------- o-norm + gate (hn_end @ Wg) + silu gating (f32) ----------------
__global__ __launch_bounds__(256,1) void gate_k(const float* __restrict__ obuf,
   const float* __restrict__ hn_ends, const float* __restrict__ Wg,
   const float* __restrict__ onw, const int* __restrict__ cu, float* __restrict__ og)
{
  __shared__ float red[4];
  __shared__ float hrow[H_DIM];
  int tid = threadIdx.x;
  int s = blockIdx.x / 6, ch = blockIdx.x % 6;
  int cc = ch*256 + tid;
  *(float4*)&hrow[tid*4] = *(const float4*)&hn_ends[(size_t)(s*4+3)*H_DIM + tid*4];
  float o = obuf[(size_t)s*VD + cc];
  float sq = o*o;
  #pragma unroll
  for (int off=1; off<64; off<<=1) sq += __shfl_xor(sq, off);
  int wv = tid>>6, lane = tid&63;
  if (lane==0) red[wv] = sq;
  __syncthreads();
  float ssum = (tid<128) ? (red[0]+red[1]) : (red[2]+red[3]);
  float onr = o * rsqrtf(ssum*(1.f/128.f) + 1e-5f) * onw[cc & 127];
  float acc = 0.f;
  for (int i0=0;i0<H_DIM;i0++)
    acc = fmaf(hrow[i0], Wg[(size_t)i0*VD + cc], acc);
  og[(size_t)s*VD + cc] = onr * acc * sigm(acc);
}

// ---------------- final: h = og@Wo + residual ; out = h@W_head + b_head (f32) ---------
__global__ __launch_bounds__(256,1) void final_k(const float* __restrict__ og,
   const float* __restrict__ Wo, const float* __restrict__ h_end,
   const float* __restrict__ W_head, const float* __restrict__ b_head,
   float* __restrict__ out)
{
  __shared__ float ogs[VD];
  __shared__ float redp[4];
  int tid = threadIdx.x;
  int s = blockIdx.x;
  for (int j=tid; j<VD; j+=256) ogs[j] = og[(size_t)s*VD + j];
  __syncthreads();
  int c0 = tid*4;
  float4 hh4 = *(const float4*)&h_end[(size_t)s*H_DIM + c0];
  float acc0 = hh4.x, acc1 = hh4.y, acc2 = hh4.z, acc3 = hh4.w;
  for (int j=0;j<VD;j++){
    float ov = ogs[j];
    float4 wo = *(const float4*)&Wo[(size_t)j*H_DIM + c0];
    acc0 = fmaf(ov,wo.x,acc0); acc1 = fmaf(ov,wo.y,acc1);
    acc2 = fmaf(ov,wo.z,acc2); acc3 = fmaf(ov,wo.w,acc3);
  }
  float4 wh = *(const float4*)&W_head[c0];
  float p = acc0*wh.x + acc1*wh.y + acc2*wh.z + acc3*wh.w;
  #pragma unroll
  for (int off=1; off<64; off<<=1) p += __shfl_xor(p, off);
  int wv = tid>>6, lane = tid&63;
  if (lane==0) redp[wv] = p;
  __syncthreads();
  if (tid==0) out[s] = redp[0]+redp[1]+redp[2]+redp[3] + b_head[0];
}

extern "C" void kernel_launch(void* const* d_in, const int* in_sizes, int n_in,
                              void* d_out, int out_size, void* d_ws, size_t ws_size,
                              hipStream_t stream)
{
  const float* x      = (const float*)d_in[0];
  const int*   cu     = (const int*)  d_in[1];
  const int*   atype  = (const int*)  d_in[2];
  const float* ac_tab = (const float*)d_in[3];
  const float* W_in   = (const float*)d_in[4];
  const float* b_in   = (const float*)d_in[5];
  const float* norm_w = (const float*)d_in[6];
  const float* Wq     = (const float*)d_in[7];
  const float* Wk     = (const float*)d_in[8];
  const float* Wv     = (const float*)d_in[9];
  const float* cqw    = (const float*)d_in[10];
  const float* ckw    = (const float*)d_in[11];
  const float* cvw    = (const float*)d_in[12];
  const float* Wb     = (const float*)d_in[13];
  const float* Wa     = (const float*)d_in[14];
  const float* A_log  = (const float*)d_in[15];
  const float* dt_b   = (const float*)d_in[16];
  const float* Wg     = (const float*)d_in[17];
  const float* onw    = (const float*)d_in[18];
  const float* Wo     = (const float*)d_in[19];
  const float* W_head = (const float*)d_in[20];
  const float* b_head = (const float*)d_in[21];
  float* out = (float*)d_out;

  // ---- workspace plan (~180 MiB peak, small buffers first) ----
  char* w = (char*)d_ws;
  int*    seg     = (int*)w;     w += (size_t)T_TOK*4;                //  0.13 MB
  float*  h_end   = (float*)w;   w += (size_t)NSEG*H_DIM*4;           //  64 KB
  float*  hn_ends = (float*)w;   w += (size_t)NSEG*4*H_DIM*4;         // 256 KB
  float*  qpre    = (float*)w;   w += (size_t)NSEG*4*KD*4;            // 192 KB
  float*  qf      = (float*)w;   w += (size_t)NSEG*KD*4;              //  48 KB
  float*  obuf    = (float*)w;   w += (size_t)NSEG*VD*4;              //  96 KB
  float*  og      = (float*)w;   w += (size_t)NSEG*VD*4;              //  96 KB
  float2* db      = (float2*)w;  w += (size_t)T_TOK*NH*8;             //  3.1 MB
  float*  ba      = (float*)w;   w += (size_t)T_TOK*32*4;             //  4.2 MB
  ushort* wt      = (ushort*)w;  w += (size_t)NCOL*H_DIM*2;           //  5.0 MB
  ushort* side    = (ushort*)w;  w += (size_t)(T_TOK/64)*3*2304*2;    //  7.1 MB
  ushort* hn_c    = (ushort*)w;  w += (size_t)CHUNK_M*H_DIM*2;        //  8.4 MB
  ushort* kpre    = (ushort*)w;  w += (size_t)T_TOK*KD*2;             // 50.3 MB
  ushort* vpre    = (ushort*)w;  w += (size_t)T_TOK*VD*2;             // 100.7 MB

  hipLaunchKernelGGL(segk,     dim3(T_TOK/256),        dim3(256), 0, stream, cu, seg);
  hipLaunchKernelGGL(build_wt, dim3((NCOL*H_DIM)/256), dim3(256), 0, stream, Wk, Wv, Wb, Wa, wt);
  for (int c = 0; c < T_TOK/CHUNK_M; c++){
    int row_base = c*CHUNK_M;
    hipLaunchKernelGGL(stage_a,  dim3(CHUNK_M/8), dim3(256), 0, stream,
                       x, atype, ac_tab, W_in, b_in, norm_w, seg, row_base, hn_c, h_end, hn_ends);
    hipLaunchKernelGGL(gemm_bf16, dim3((CHUNK_M/128)*(NCOL/128)), dim3(256), 0, stream,
                       hn_c, wt, row_base, kpre, vpre, ba);
  }
  hipLaunchKernelGGL(dbk,      dim3((T_TOK*NH)/256),   dim3(256), 0, stream, ba, A_log, dt_b, db);
  hipLaunchKernelGGL(side_k,   dim3(T_TOK/64),         dim3(256), 0, stream, kpre, vpre, side);
  hipLaunchKernelGGL(conv_ip,  dim3(T_TOK/64),         dim3(256), 0, stream, kpre, vpre, side, seg, ckw, cvw);
  hipLaunchKernelGGL(qpre_k,   dim3(NSEG*4),           dim3(256), 0, stream, hn_ends, Wq, cu, qpre);
  hipLaunchKernelGGL(qfin_k,   dim3(NSEG),             dim3(256), 0, stream, qpre, cqw, cu, seg, qf);
  hipLaunchKernelGGL(scan_k,   dim3(NSEG*NH*8),        dim3(128), 0, stream, kpre, vpre, db, qf, cu, obuf);
  hipLaunchKernelGGL(gate_k,   dim3(NSEG*6),           dim3(256), 0, stream, obuf, hn_ends, Wg, onw, cu, og);
  hipLaunchKernelGGL(final_k,  dim3(NSEG),             dim3(256), 0, stream, og, Wo, h_end, W_head, b_head, out);
}

// Round 6
// 2424.794 us; speedup vs baseline: 1.5946x; 1.5545x over previous
//
#include <hip/hip_runtime.h>
#include <stdint.h>

#define T_TOK 32768
#define H_DIM 1024
#define NH    12
#define HK    64
#define HV    128
#define KD    768
#define VD    1536
#define NSEG  16
#define NCOL  2432   // GEMM logical N: 768 k + 1536 v + 24 ba + pad -> 19*128
#define FEAT  48
#define CHUNK_M 4096

typedef unsigned int uint;
typedef unsigned short ushort;

typedef short bf16x8_t __attribute__((ext_vector_type(8)));
typedef float f32x4_t  __attribute__((ext_vector_type(4)));

__device__ __forceinline__ ushort f2b(float f){
  uint u = __float_as_uint(f);
  u += 0x7fffu + ((u>>16)&1u);           // round-to-nearest-even
  return (ushort)(u>>16);
}
__device__ __forceinline__ float b2f(ushort u){ return __uint_as_float(((uint)u)<<16); }
__device__ __forceinline__ void unpack2(uint u, float&a, float&b){
  a = __uint_as_float(u<<16); b = __uint_as_float(u & 0xffff0000u);
}
__device__ __forceinline__ float sigm(float x){ return 1.f/(1.f + __expf(-x)); }
__device__ __forceinline__ float silu(float x){ return x * sigm(x); }

// ---------------- seg_id ----------------
__global__ void segk(const int* __restrict__ cu, int* __restrict__ seg){
  int t = blockIdx.x*256 + threadIdx.x;
  if (t >= T_TOK) return;
  int s = 0;
  #pragma unroll
  for (int i=1;i<=NSEG;i++) s += (cu[i] <= t) ? 1 : 0;
  seg[t] = s;
}

// ---------------- stage A (chunked, f32 in): h = feat@W_in + b_in ; hn = zc_rmsnorm(h)
__global__ __launch_bounds__(256,1) void stage_a(const float* __restrict__ x,
   const int* __restrict__ atype, const float* __restrict__ ac_table,
   const float* __restrict__ W_in, const float* __restrict__ b_in,
   const float* __restrict__ norm_w, const int* __restrict__ seg, int row_base,
   ushort* __restrict__ hn, float* __restrict__ h_end, float* __restrict__ hn_ends)
{
  __shared__ float feat[8][FEAT];
  __shared__ float hbuf[8][H_DIM];
  __shared__ float red[8];
  int tid = threadIdx.x;
  int base = row_base + blockIdx.x*8;      // global row of slot 0
  int lbase = blockIdx.x*8;                // local row in hn chunk
  if (tid < 8) red[tid] = 0.f;
  for (int idx=tid; idx<8*FEAT; idx+=256){
    int rr = idx / FEAT, i = idx % FEAT;
    int t = base + rr;
    float v;
    if (i < 16) v = x[t*16 + i];
    else { int s = seg[t]; int a = atype[s]; v = ac_table[a*32 + (i-16)]; }
    feat[rr][i] = v;
  }
  __syncthreads();
  int c0 = tid*4;
  int lane = tid & 63;
  float4 bi = *(const float4*)&b_in[c0];
  for (int rc=0; rc<2; rc++){
    float acc[4][4];
    #pragma unroll
    for (int r4=0;r4<4;r4++){ acc[r4][0]=bi.x; acc[r4][1]=bi.y; acc[r4][2]=bi.z; acc[r4][3]=bi.w; }
    for (int i=0;i<FEAT;i++){
      float4 wu = *(const float4*)&W_in[i*H_DIM + c0];
      #pragma unroll
      for (int r4=0;r4<4;r4++){
        float f = feat[rc*4+r4][i];
        acc[r4][0] = fmaf(f,wu.x,acc[r4][0]);
        acc[r4][1] = fmaf(f,wu.y,acc[r4][1]);
        acc[r4][2] = fmaf(f,wu.z,acc[r4][2]);
        acc[r4][3] = fmaf(f,wu.w,acc[r4][3]);
      }
    }
    #pragma unroll
    for (int r4=0;r4<4;r4++){
      int rr = rc*4+r4;
      float sq = acc[r4][0]*acc[r4][0] + acc[r4][1]*acc[r4][1]
               + acc[r4][2]*acc[r4][2] + acc[r4][3]*acc[r4][3];
      #pragma unroll
      for (int off=1; off<64; off<<=1) sq += __shfl_xor(sq, off);
      if (lane==0) atomicAdd(&red[rr], sq);
      hbuf[rr][c0]=acc[r4][0]; hbuf[rr][c0+1]=acc[r4][1];
      hbuf[rr][c0+2]=acc[r4][2]; hbuf[rr][c0+3]=acc[r4][3];
    }
  }
  __syncthreads();
  float4 nw = *(const float4*)&norm_w[c0];
  for (int rr=0; rr<8; rr++){
    int t = base + rr;
    float sc = rsqrtf(red[rr]*(1.f/1024.f) + 1e-6f);
    float h0=hbuf[rr][c0], h1=hbuf[rr][c0+1], h2=hbuf[rr][c0+2], h3=hbuf[rr][c0+3];
    float n0=h0*sc*(1.f+nw.x), n1=h1*sc*(1.f+nw.y);
    float n2=h2*sc*(1.f+nw.z), n3=h3*sc*(1.f+nw.w);
    uint2 ov; ov.x = (uint)f2b(n0) | ((uint)f2b(n1)<<16);
    ov.y = (uint)f2b(n2) | ((uint)f2b(n3)<<16);
    *(uint2*)&hn[(size_t)(lbase+rr)*H_DIM + c0] = ov;
    int sgt = seg[t];
    bool isend = (t == T_TOK-1) || (seg[t+1] != sgt);
    if (isend){
      float* he = h_end + (size_t)sgt*H_DIM + c0;
      he[0]=h0; he[1]=h1; he[2]=h2; he[3]=h3;
    }
    #pragma unroll
    for (int d=0; d<4; d++){
      int td = t + d;
      if (td < T_TOK && seg[td] == sgt){
        bool end2 = (td == T_TOK-1) || (seg[td+1] != sgt);
        if (end2){
          float* hd = hn_ends + ((size_t)sgt*4 + (3-d))*H_DIM + c0;
          hd[0]=n0; hd[1]=n1; hd[2]=n2; hd[3]=n3;
        }
      }
    }
  }
}

// ---------------- build fused transposed weight wt[n][k] (f32 -> bf16) ----------------
__global__ void build_wt(const float* __restrict__ Wk, const float* __restrict__ Wv,
                         const float* __restrict__ Wb, const float* __restrict__ Wa,
                         ushort* __restrict__ wt)
{
  int idx = blockIdx.x*256 + threadIdx.x;      // idx = n*1024 + k
  int n = idx >> 10, k = idx & 1023;
  float v;
  if      (n < 768)  v = Wk[k*768 + n];
  else if (n < 2304) v = Wv[k*1536 + (n-768)];
  else if (n < 2316) v = Wb[k*12 + (n-2304)];
  else if (n < 2328) v = Wa[k*12 + (n-2316)];
  else               v = 0.f;
  wt[idx] = f2b(v);
}

// ---------------- chunked MFMA GEMM over hn_chunk, outputs kpre/vpre (bf16), ba (f32) --
__global__ __launch_bounds__(256,1) void gemm_bf16(const ushort* __restrict__ A,
    const ushort* __restrict__ Bt, int row_base,
    ushort* __restrict__ kpre, ushort* __restrict__ vpre, float* __restrict__ ba)
{
  const int K = H_DIM;
  __shared__ ushort As[128*40];
  __shared__ ushort Bs[128*40];
  int tid = threadIdx.x;
  const int ntile = NCOL >> 7;   // 19
  int mt = blockIdx.x / ntile, nt = blockIdx.x % ntile;
  int m0 = mt<<7, n0 = nt<<7;    // m0 is LOCAL to chunk
  int r = tid>>2, c8 = (tid&3)<<3;
  const ushort* pa0 = A  + (size_t)(m0 + r)*K + c8;
  const ushort* pa1 = A  + (size_t)(m0 + r + 64)*K + c8;
  const ushort* pb0 = Bt + (size_t)(n0 + r)*K + c8;
  const ushort* pb1 = Bt + (size_t)(n0 + r + 64)*K + c8;
  int lane = tid & 63;
  int wv = tid >> 6; int wm = (wv>>1)<<6, wn = (wv&1)<<6;
  int mloc = lane & 15, q8 = (lane>>4)<<3;
  f32x4_t acc[4][4];
  f32x4_t zero = {0.f,0.f,0.f,0.f};
  #pragma unroll
  for (int i=0;i<4;i++)
    #pragma unroll
    for (int j=0;j<4;j++) acc[i][j] = zero;
  for (int kk=0; kk<K; kk+=32){
    uint4 a0 = *(const uint4*)(pa0 + kk);
    uint4 a1 = *(const uint4*)(pa1 + kk);
    uint4 b0 = *(const uint4*)(pb0 + kk);
    uint4 b1 = *(const uint4*)(pb1 + kk);
    __syncthreads();
    *(uint4*)&As[r*40 + c8] = a0;
    *(uint4*)&As[(r+64)*40 + c8] = a1;
    *(uint4*)&Bs[r*40 + c8] = b0;
    *(uint4*)&Bs[(r+64)*40 + c8] = b1;
    __syncthreads();
    bf16x8_t af[4], bfr[4];
    #pragma unroll
    for (int i=0;i<4;i++){
      af[i]  = *(const bf16x8_t*)&As[(wm + i*16 + mloc)*40 + q8];
      bfr[i] = *(const bf16x8_t*)&Bs[(wn + i*16 + mloc)*40 + q8];
    }
    #pragma unroll
    for (int i=0;i<4;i++)
      #pragma unroll
      for (int j=0;j<4;j++)
        acc[i][j] = __builtin_amdgcn_mfma_f32_16x16x32_bf16(af[i], bfr[j], acc[i][j], 0,0,0);
  }
  int rq = (lane>>4)<<2;
  if (nt < 18){
    ushort* dst; int nstr, cbase;
    if (nt < 6) { dst = kpre; nstr = KD; cbase = n0; }
    else        { dst = vpre; nstr = VD; cbase = n0 - KD; }
    #pragma unroll
    for (int i=0;i<4;i++){
      #pragma unroll
      for (int j=0;j<4;j++){
        int colg = cbase + wn + j*16 + mloc;
        #pragma unroll
        for (int rg=0; rg<4; rg++){
          int rowg = row_base + m0 + wm + i*16 + rq + rg;
          dst[(size_t)rowg*nstr + colg] = f2b(acc[i][j][rg]);
        }
      }
    }
  } else {
    #pragma unroll
    for (int i=0;i<4;i++){
      #pragma unroll
      for (int j=0;j<4;j++){
        int cl = wn + j*16 + mloc;        // 0..127 within tile
        if (cl >= 24) continue;
        #pragma unroll
        for (int rg=0; rg<4; rg++){
          int rowg = row_base + m0 + wm + i*16 + rq + rg;
          ba[(size_t)rowg*32 + cl] = acc[i][j][rg];
        }
      }
    }
  }
}

// ---------------- decay/beta from ba (f32) ----------------
__global__ void dbk(const float* __restrict__ ba, const float* __restrict__ A_log,
                    const float* __restrict__ dt_bias, float2* __restrict__ db)
{
  int idx = blockIdx.x*256 + threadIdx.x;
  if (idx >= T_TOK*NH) return;
  int t = idx / NH, hh = idx % NH;
  float bp = ba[(size_t)t*32 + hh];
  float ap = ba[(size_t)t*32 + 12 + hh] + dt_bias[hh];
  float beta = sigm(bp);
  float sp = (ap > 20.f) ? ap : log1pf(__expf(ap));
  float dec = __expf(-__expf(A_log[hh]) * sp);
  float2 o; o.x = dec; o.y = beta;
  db[idx] = o;
}

// ---------------- side: save 3 predecessor rows per 64-row conv block ----------------
__global__ void side_k(const ushort* __restrict__ kpre, const ushort* __restrict__ vpre,
                       ushort* __restrict__ side)
{
  int b = blockIdx.x;                 // T/64 blocks
  int base = b*64;
  for (int idx=threadIdx.x; idx<3*2304; idx+=256){
    int jrow = idx / 2304, c = idx % 2304;
    int t0 = base - 3 + jrow;
    ushort v = 0;
    if (t0 >= 0)
      v = (c < KD) ? kpre[(size_t)t0*KD + c] : vpre[(size_t)t0*VD + (c-KD)];
    side[(size_t)(b*3 + jrow)*2304 + c] = v;
  }
}

// ---------------- conv+silu (+l2norm for k) IN PLACE on kpre/vpre ----------------
__global__ __launch_bounds__(256,1) void conv_ip(ushort* __restrict__ kpre,
   ushort* __restrict__ vpre, const ushort* __restrict__ side,
   const int* __restrict__ seg, const float* __restrict__ ckw, const float* __restrict__ cvw)
{
  int tid = threadIdx.x;
  int b = blockIdx.x;
  int base = b * 64;
  float w[9][4];
  int cj[9];
  #pragma unroll
  for (int j=0;j<9;j++){
    int c = tid + 256*j;
    cj[j] = c;
    float4 wu = (c < KD) ? *(const float4*)&ckw[c*4] : *(const float4*)&cvw[(c-KD)*4];
    w[j][0]=wu.x; w[j][1]=wu.y; w[j][2]=wu.z; w[j][3]=wu.w;
  }
  float p[9][4];
  #pragma unroll
  for (int j=0;j<9;j++){
    p[j][1] = b2f(side[(size_t)(b*3+0)*2304 + cj[j]]);
    p[j][2] = b2f(side[(size_t)(b*3+1)*2304 + cj[j]]);
    p[j][3] = b2f(side[(size_t)(b*3+2)*2304 + cj[j]]);
  }
  int s1 = (base-3>=0) ? seg[base-3] : -1;
  int s2 = (base-2>=0) ? seg[base-2] : -1;
  int s3 = (base-1>=0) ? seg[base-1] : -1;
  int s0;
  for (int rr=0; rr<64; rr++){
    int t = base + rr;
    s0 = s1; s1 = s2; s2 = s3; s3 = seg[t];
    #pragma unroll
    for (int j=0;j<9;j++){
      p[j][0]=p[j][1]; p[j][1]=p[j][2]; p[j][2]=p[j][3];
      int c = cj[j];
      p[j][3] = (c < KD) ? b2f(kpre[(size_t)t*KD + c]) : b2f(vpre[(size_t)t*VD + (c-KD)]);
    }
    bool m0 = (s0==s3), m1 = (s1==s3), m2 = (s2==s3);
    #pragma unroll
    for (int j=0;j<9;j++){
      float val = p[j][3]*w[j][3];
      val += m2 ? p[j][2]*w[j][2] : 0.f;
      val += m1 ? p[j][1]*w[j][1] : 0.f;
      val += m0 ? p[j][0]*w[j][0] : 0.f;
      val = silu(val);
      int c = cj[j];
      if (j < 3){
        float sq = val*val;
        #pragma unroll
        for (int off=1; off<64; off<<=1) sq += __shfl_xor(sq, off);
        float kn = val * rsqrtf(sq + 1e-6f);
        kpre[(size_t)t*KD + c] = f2b(kn);
      } else {
        vpre[(size_t)t*VD + (c-KD)] = f2b(val);
      }
    }
  }
}

// ---------------- q pre-GEMM at (up to) 64 saved rows (all f32) ----------------
__global__ __launch_bounds__(256,1) void qpre_k(const float* __restrict__ hn_ends,
   const float* __restrict__ Wq, const int* __restrict__ cu, float* __restrict__ qpre)
{
  __shared__ float hrow[H_DIM];
  int tid = threadIdx.x;
  int s = blockIdx.x >> 2, rr = blockIdx.x & 3;
  int t = cu[s+1] - 4 + rr;
  if (t >= 0)
    *(float4*)&hrow[tid*4] = *(const float4*)&hn_ends[(size_t)(s*4+rr)*H_DIM + tid*4];
  __syncthreads();
  for (int j=0;j<3;j++){
    int c = tid + 256*j;
    float acc = 0.f;
    if (t >= 0){
      for (int i0=0; i0<H_DIM; i0++)
        acc = fmaf(hrow[i0], Wq[(size_t)i0*KD + c], acc);
    }
    qpre[(size_t)(s*4+rr)*KD + c] = acc;
  }
}

// ---------------- q conv+silu+l2norm+scale at 16 end rows ----------------
__global__ __launch_bounds__(256,1) void qfin_k(const float* __restrict__ qpre,
   const float* __restrict__ cqw, const int* __restrict__ cu, const int* __restrict__ seg,
   float* __restrict__ qf)
{
  int tid = threadIdx.x;
  int s = blockIdx.x;
  int te = cu[s+1]-1;
  for (int j=0;j<3;j++){
    int c = tid + 256*j;
    float4 wu = *(const float4*)&cqw[c*4];
    float wv_[4] = {wu.x, wu.y, wu.z, wu.w};
    float val = 0.f;
    #pragma unroll
    for (int rr=0; rr<4; rr++){
      int t = te - 3 + rr;
      bool ok = (t >= 0) && (seg[t] == s);
      float pv = qpre[(size_t)(s*4+rr)*KD + c];
      val += ok ? pv * wv_[rr] : 0.f;
    }
    val = silu(val);
    float sq = val*val;
    #pragma unroll
    for (int off=1; off<64; off<<=1) sq += __shfl_xor(sq, off);
    qf[(size_t)s*KD + c] = val * rsqrtf(sq + 1e-6f) * 0.125f;   // HK^-0.5 folded
  }
}

// ---------------- gated delta-rule scan, 8-deep register pipeline -------------
// Named slot variables (no arrays -> no scratch demotion); guard-free main loop.
// grid mapping: (s,h) = bid % 192, vb = bid / 192 so the 8 vb sharing one
// k-stream land on the same XCD (192 % 8 == 0) for L2 reuse.
__global__ __launch_bounds__(128,1) void scan_k(const ushort* __restrict__ kpost,
   const ushort* __restrict__ vpost, const float2* __restrict__ db,
   const float* __restrict__ qf, const int* __restrict__ cu, float* __restrict__ obuf)
{
  int bid = blockIdx.x;
  int sh = bid % (NSEG*NH); int vb = bid / (NSEG*NH);
  int s = sh / NH, h = sh % NH;
  int tid = threadIdx.x;
  int vl = tid >> 3, kq = tid & 7;
  int start = cu[s], end = cu[s+1];
  int e1 = end - 1;
  float S[8];
  #pragma unroll
  for (int i=0;i<8;i++) S[i] = 0.f;
  const ushort* kbase = kpost + h*HK + kq*8;
  const ushort* vbase = vpost + h*HV + vb*16 + vl;
  const float2* dbase = db + h;

#define LK(tt) (*(const uint4*)(kbase + (size_t)(tt)*KD))
#define LV(tt) (vbase[(size_t)(tt)*VD])
#define LD_(tt) (dbase[(size_t)(tt)*NH])

#define SCAN_STEP(kc, vc, gc) {                                            \
    float kk0,kk1,kk2,kk3,kk4,kk5,kk6,kk7;                                 \
    unpack2(kc.x, kk0, kk1); unpack2(kc.y, kk2, kk3);                      \
    unpack2(kc.z, kk4, kk5); unpack2(kc.w, kk6, kk7);                      \
    float a0 = kk0*S[0], a1 = kk1*S[1];                                    \
    a0 = fmaf(kk2, S[2], a0); a1 = fmaf(kk3, S[3], a1);                    \
    a0 = fmaf(kk4, S[4], a0); a1 = fmaf(kk5, S[5], a1);                    \
    a0 = fmaf(kk6, S[6], a0); a1 = fmaf(kk7, S[7], a1);                    \
    float kv = a0 + a1;                                                    \
    kv += __shfl_xor(kv, 1); kv += __shfl_xor(kv, 2); kv += __shfl_xor(kv, 4); \
    float wu = gc.y * (b2f(vc) - gc.x*kv);                                 \
    S[0] = fmaf(S[0], gc.x, kk0*wu); S[1] = fmaf(S[1], gc.x, kk1*wu);      \
    S[2] = fmaf(S[2], gc.x, kk2*wu); S[3] = fmaf(S[3], gc.x, kk3*wu);      \
    S[4] = fmaf(S[4], gc.x, kk4*wu); S[5] = fmaf(S[5], gc.x, kk5*wu);      \
    S[6] = fmaf(S[6], gc.x, kk6*wu); S[7] = fmaf(S[7], gc.x, kk7*wu);      \
  }

  // prologue: fill 8 slots (clamped)
  int p1=min(start+1,e1), p2=min(start+2,e1), p3=min(start+3,e1);
  int p4=min(start+4,e1), p5=min(start+5,e1), p6=min(start+6,e1), p7=min(start+7,e1);
  uint4  k0=LK(start), k1=LK(p1), k2=LK(p2), k3=LK(p3), k4=LK(p4), k5=LK(p5), k6=LK(p6), k7=LK(p7);
  ushort v0=LV(start), v1=LV(p1), v2=LV(p2), v3=LV(p3), v4=LV(p4), v5=LV(p5), v6=LV(p6), v7=LV(p7);
  float2 g0=LD_(start), g1=LD_(p1), g2=LD_(p2), g3=LD_(p3), g4=LD_(p4), g5=LD_(p5), g6=LD_(p6), g7=LD_(p7);

  int t = start;
  while (t + 8 <= end){
    int tn = t + 8;
    int r0=min(tn,e1),   r1=min(tn+1,e1), r2=min(tn+2,e1), r3=min(tn+3,e1);
    int r4=min(tn+4,e1), r5=min(tn+5,e1), r6=min(tn+6,e1), r7=min(tn+7,e1);
    { uint4 kc=k0; ushort vc=v0; float2 gc=g0; k0=LK(r0); v0=LV(r0); g0=LD_(r0); SCAN_STEP(kc,vc,gc); }
    { uint4 kc=k1; ushort vc=v1; float2 gc=g1; k1=LK(r1); v1=LV(r1); g1=LD_(r1); SCAN_STEP(kc,vc,gc); }
    { uint4 kc=k2; ushort vc=v2; float2 gc=g2; k2=LK(r2); v2=LV(r2); g2=LD_(r2); SCAN_STEP(kc,vc,gc); }
    { uint4 kc=k3; ushort vc=v3; float2 gc=g3; k3=LK(r3); v3=LV(r3); g3=LD_(r3); SCAN_STEP(kc,vc,gc); }
    { uint4 kc=k4; ushort vc=v4; float2 gc=g4; k4=LK(r4); v4=LV(r4); g4=LD_(r4); SCAN_STEP(kc,vc,gc); }
    { uint4 kc=k5; ushort vc=v5; float2 gc=g5; k5=LK(r5); v5=LV(r5); g5=LD_(r5); SCAN_STEP(kc,vc,gc); }
    { uint4 kc=k6; ushort vc=v6; float2 gc=g6; k6=LK(r6); v6=LV(r6); g6=LD_(r6); SCAN_STEP(kc,vc,gc); }
    { uint4 kc=k7; ushort vc=v7; float2 gc=g7; k7=LK(r7); v7=LV(r7); g7=LD_(r7); SCAN_STEP(kc,vc,gc); }
    t = tn;
  }
  int rem = end - t;     // 0..7
  if (rem > 0) SCAN_STEP(k0,v0,g0);
  if (rem > 1) SCAN_STEP(k1,v1,g1);
  if (rem > 2) SCAN_STEP(k2,v2,g2);
  if (rem > 3) SCAN_STEP(k3,v3,g3);
  if (rem > 4) SCAN_STEP(k4,v4,g4);
  if (rem > 5) SCAN_STEP(k5,v5,g5);
  if (rem > 6) SCAN_STEP(k6,v6,g6);

  float op = 0.f;
  const float* qp = qf + (size_t)s*KD + h*HK + kq*8;
  #pragma unroll
  for (int i=0;i<8;i++) op = fmaf(qp[i], S[i], op);
  op += __shfl_xor(op, 1); op += __shfl_xor(op, 2); op += __shfl_xor(op, 4);
  if (kq == 0) obuf[(size_t)s*VD + h*HV + vb*16 + vl] = op;
#undef LK
#undef LV
#undef LD_
#undef SCAN_STEP
}

// ---------------- o-norm + gate (hn_end @ Wg) + silu gating (f32) ----------------
__global__ __launch_bounds__(256,1) void gate_k(const float* __restrict__ obuf,
   const float* __restrict__ hn_ends, const float* __restrict__ Wg,
   const float* __restrict__ onw, const int* __restrict__ cu, float* __restrict__ og)
{
  __shared__ float red[4];
  __shared__ float hrow[H_DIM];
  int tid = threadIdx.x;
  int s = blockIdx.x / 6, ch = blockIdx.x % 6;
  int cc = ch*256 + tid;
  *(float4*)&hrow[tid*4] = *(const float4*)&hn_ends[(size_t)(s*4+3)*H_DIM + tid*4];
  float o = obuf[(size_t)s*VD + cc];
  float sq = o*o;
  #pragma unroll
  for (int off=1; off<64; off<<=1) sq += __shfl_xor(sq, off);
  int wv = tid>>6, lane = tid&63;
  if (lane==0) red[wv] = sq;
  __syncthreads();
  float ssum = (tid<128) ? (red[0]+red[1]) : (red[2]+red[3]);
  float onr = o * rsqrtf(ssum*(1.f/128.f) + 1e-5f) * onw[cc & 127];
  float acc = 0.f;
  for (int i0=0;i0<H_DIM;i0++)
    acc = fmaf(hrow[i0], Wg[(size_t)i0*VD + cc], acc);
  og[(size_t)s*VD + cc] = onr * acc * sigm(acc);
}

// ---------------- final: h = og@Wo + residual ; out = h@W_head + b_head (f32) ---------
__global__ __launch_bounds__(256,1) void final_k(const float* __restrict__ og,
   const float* __restrict__ Wo, const float* __restrict__ h_end,
   const float* __restrict__ W_head, const float* __restrict__ b_head,
   float* __restrict__ out)
{
  __shared__ float ogs[VD];
  __shared__ float redp[4];
  int tid = threadIdx.x;
  int s = blockIdx.x;
  for (int j=tid; j<VD; j+=256) ogs[j] = og[(size_t)s*VD + j];
  __syncthreads();
  int c0 = tid*4;
  float4 hh4 = *(const float4*)&h_end[(size_t)s*H_DIM + c0];
  float acc0 = hh4.x, acc1 = hh4.y, acc2 = hh4.z, acc3 = hh4.w;
  for (int j=0;j<VD;j++){
    float ov = ogs[j];
    float4 wo = *(const float4*)&Wo[(size_t)j*H_DIM + c0];
    acc0 = fmaf(ov,wo.x,acc0); acc1 = fmaf(ov,wo.y,acc1);
    acc2 = fmaf(ov,wo.z,acc2); acc3 = fmaf(ov,wo.w,acc3);
  }
  float4 wh = *(const float4*)&W_head[c0];
  float p = acc0*wh.x + acc1*wh.y + acc2*wh.z + acc3*wh.w;
  #pragma unroll
  for (int off=1; off<64; off<<=1) p += __shfl_xor(p, off);
  int wv = tid>>6, lane = tid&63;
  if (lane==0) redp[wv] = p;
  __syncthreads();
  if (tid==0) out[s] = redp[0]+redp[1]+redp[2]+redp[3] + b_head[0];
}

extern "C" void kernel_launch(void* const* d_in, const int* in_sizes, int n_in,
                              void* d_out, int out_size, void* d_ws, size_t ws_size,
                              hipStream_t stream)
{
  const float* x      = (const float*)d_in[0];
  const int*   cu     = (const int*)  d_in[1];
  const int*   atype  = (const int*)  d_in[2];
  const float* ac_tab = (const float*)d_in[3];
  const float* W_in   = (const float*)d_in[4];
  const float* b_in   = (const float*)d_in[5];
  const float* norm_w = (const float*)d_in[6];
  const float* Wq     = (const float*)d_in[7];
  const float* Wk     = (const float*)d_in[8];
  const float* Wv     = (const float*)d_in[9];
  const float* cqw    = (const float*)d_in[10];
  const float* ckw    = (const float*)d_in[11];
  const float* cvw    = (const float*)d_in[12];
  const float* Wb     = (const float*)d_in[13];
  const float* Wa     = (const float*)d_in[14];
  const float* A_log  = (const float*)d_in[15];
  const float* dt_b   = (const float*)d_in[16];
  const float* Wg     = (const float*)d_in[17];
  const float* onw    = (const float*)d_in[18];
  const float* Wo     = (const float*)d_in[19];
  const float* W_head = (const float*)d_in[20];
  const float* b_head = (const float*)d_in[21];
  float* out = (float*)d_out;

  // ---- workspace plan (~180 MiB peak, small buffers first) ----
  char* w = (char*)d_ws;
  int*    seg     = (int*)w;     w += (size_t)T_TOK*4;                //  0.13 MB
  float*  h_end   = (float*)w;   w += (size_t)NSEG*H_DIM*4;           //  64 KB
  float*  hn_ends = (float*)w;   w += (size_t)NSEG*4*H_DIM*4;         // 256 KB
  float*  qpre    = (float*)w;   w += (size_t)NSEG*4*KD*4;            // 192 KB
  float*  qf      = (float*)w;   w += (size_t)NSEG*KD*4;              //  48 KB
  float*  obuf    = (float*)w;   w += (size_t)NSEG*VD*4;              //  96 KB
  float*  og      = (float*)w;   w += (size_t)NSEG*VD*4;              //  96 KB
  float2* db      = (float2*)w;  w += (size_t)T_TOK*NH*8;             //  3.1 MB
  float*  ba      = (float*)w;   w += (size_t)T_TOK*32*4;             //  4.2 MB
  ushort* wt      = (ushort*)w;  w += (size_t)NCOL*H_DIM*2;           //  5.0 MB
  ushort* side    = (ushort*)w;  w += (size_t)(T_TOK/64)*3*2304*2;    //  7.1 MB
  ushort* hn_c    = (ushort*)w;  w += (size_t)CHUNK_M*H_DIM*2;        //  8.4 MB
  ushort* kpre    = (ushort*)w;  w += (size_t)T_TOK*KD*2;             // 50.3 MB
  ushort* vpre    = (ushort*)w;  w += (size_t)T_TOK*VD*2;             // 100.7 MB

  hipLaunchKernelGGL(segk,     dim3(T_TOK/256),        dim3(256), 0, stream, cu, seg);
  hipLaunchKernelGGL(build_wt, dim3((NCOL*H_DIM)/256), dim3(256), 0, stream, Wk, Wv, Wb, Wa, wt);
  for (int c = 0; c < T_TOK/CHUNK_M; c++){
    int row_base = c*CHUNK_M;
    hipLaunchKernelGGL(stage_a,  dim3(CHUNK_M/8), dim3(256), 0, stream,
                       x, atype, ac_tab, W_in, b_in, norm_w, seg, row_base, hn_c, h_end, hn_ends);
    hipLaunchKernelGGL(gemm_bf16, dim3((CHUNK_M/128)*(NCOL/128)), dim3(256), 0, stream,
                       hn_c, wt, row_base, kpre, vpre, ba);
  }
  hipLaunchKernelGGL(dbk,      dim3((T_TOK*NH)/256),   dim3(256), 0, stream, ba, A_log, dt_b, db);
  hipLaunchKernelGGL(side_k,   dim3(T_TOK/64),         dim3(256), 0, stream, kpre, vpre, side);
  hipLaunchKernelGGL(conv_ip,  dim3(T_TOK/64),         dim3(256), 0, stream, kpre, vpre, side, seg, ckw, cvw);
  hipLaunchKernelGGL(qpre_k,   dim3(NSEG*4),           dim3(256), 0, stream, hn_ends, Wq, cu, qpre);
  hipLaunchKernelGGL(qfin_k,   dim3(NSEG),             dim3(256), 0, stream, qpre, cqw, cu, seg, qf);
  hipLaunchKernelGGL(scan_k,   dim3(NSEG*NH*8),        dim3(128), 0, stream, kpre, vpre, db, qf, cu, obuf);
  hipLaunchKernelGGL(gate_k,   dim3(NSEG*6),           dim3(256), 0, stream, obuf, hn_ends, Wg, onw, cu, og);
  hipLaunchKernelGGL(final_k,  dim3(NSEG),             dim3(256), 0, stream, og, Wo, h_end, W_head, b_head, out);
}